// Round 6
// baseline (581.008 us; speedup 1.0000x reference)
//
#include <hip/hip_runtime.h>
#include <stdint.h>

// DilatedMask v5: single-pass producer-consumer. Every internal restructure of
// the two-kernel split tied at ~223.6-224.7us (K1 VALU-heavy vs -free: tie;
// K2 3-barrier vs 1-barrier: tie) -> the slack is the inter-kernel phase
// serialization: all 128MiB of reads must drain before any of the 128MiB of
// writes start. Fix: one kernel; block packs its 8 rows (proven K1 inner),
// fence+flag, spin-waits on the <=5 blocks producing its 40-row halo (agent
// scope), then dilates+stores (proven v4 path). Reads and writes overlap
// chip-wide. Deadlock-free without co-residency: no block waits before
// producing, and forward deps reach <= raw-bid+16, so the dispatch window
// always advances. Flags live in poisoned ws -> tiny init kernel zeroes them.

#define HH 2048
#define WPX 2048
#define WW 32            // uint64 words per row (2048 bits)
#define RAD 16
#define ROWS 8           // rows packed & dilated per block
#define SR (ROWS + 2 * RAD)   // 40 staged rows
#define TPB 256
#define NBLK 2048        // 8 images * 256 blocks

typedef int vint4 __attribute__((ext_vector_type(4)));

__global__ __launch_bounds__(256) void init_flags(unsigned* __restrict__ flags) {
  flags[blockIdx.x * 256 + threadIdx.x] = 0u;   // 8 blocks x 256 = 2048 flags
}

__global__ __launch_bounds__(TPB, 8) void pc_kernel(const float* __restrict__ x,
                                                    uint64_t* __restrict__ packed,
                                                    unsigned* __restrict__ flags,
                                                    int* __restrict__ out) {
  __shared__ uint64_t stage[SR][WW];            // 10 KiB

  const int bid = blockIdx.x;
  // XCD swizzle: halo producers (b+-1,2) co-resident on one XCD's L2.
  // Cross-chunk deps map to much earlier raw bids (safe for window progress).
  const int b = ((bid & 7) << 8) | (bid >> 3);  // NBLK=2048 -> 256 per chunk
  const int t = threadIdx.x;
  const int lane = t & 63;
  const int wv = t >> 6;                        // 0..3

  const int gr0 = b * ROWS;                     // 2048 % 8 == 0: no image straddle
  const int n = gr0 >> 11;
  const int h0 = gr0 & (HH - 1);

  // ---- pack: 8 rows, 2 per wave; lane l's j-th load is px j*64+l so each
  // ballot IS a raster-order packed word (proven v3/v4 K1 inner loop).
  {
    const float* xr = x + (long long)gr0 * WPX;
    uint64_t* prow = packed + (long long)gr0 * WW;
#pragma unroll
    for (int rr = 0; rr < 2; ++rr) {
      const int row = (wv << 1) + rr;
      const float* rp = xr + (long long)row * WPX + lane;
      uint64_t* pw = prow + row * WW;
#pragma unroll
      for (int bch = 0; bch < 4; ++bch) {
        float v[8];
#pragma unroll
        for (int j = 0; j < 8; ++j)
          v[j] = __builtin_nontemporal_load(rp + (((bch << 3) + j) << 6));
#pragma unroll
        for (int j = 0; j < 8; ++j) {
          const unsigned long long m = __ballot(v[j] == 0.0f);
          if (lane == j) pw[(bch << 3) + j] = m;   // normal store: stays in L2
        }
      }
    }
  }
  __threadfence();                              // packed visible device-wide
  __syncthreads();
  if (t == 0)
    __hip_atomic_store(&flags[b], 1u, __ATOMIC_RELEASE, __HIP_MEMORY_SCOPE_AGENT);

  // ---- wait for halo producers: rows [gr0-16, gr0+23] clamped to image ->
  // blocks b-2..b+2 clamped to this image's block range. 5 polling lanes.
  const int img_b0 = n << 8;                    // 256 blocks per image
  const int img_b1 = img_b0 + 255;
  if (t < 5) {
    int nb = b - 2 + t;
    nb = nb < img_b0 ? img_b0 : (nb > img_b1 ? img_b1 : nb);
    while (__hip_atomic_load(&flags[nb], __ATOMIC_ACQUIRE,
                             __HIP_MEMORY_SCOPE_AGENT) == 0u)
      __builtin_amdgcn_s_sleep(4);
  }
  __syncthreads();

  // ---- stage 40 packed rows from global (L2-resident, ~10 KiB), clamped
  {
    const uint64_t* base = packed + (((long long)n << 11) * WW);
#pragma unroll
    for (int i = 0; i < SR * WW / TPB; ++i) {   // 5 iters
      const int idx = i * TPB + t;
      const int rr = idx >> 5;
      const int w_ = idx & 31;
      int hh = h0 + rr - RAD;
      hh = hh < 0 ? 0 : (hh > HH - 1 ? HH - 1 : hh);  // clamp == clipped SAME
      stage[rr][w_] = base[hh * WW + w_];
    }
  }
  __syncthreads();

  // ---- dilate + store (proven v4 path): 2 rows/wave, vertical OR from LDS,
  // horizontal OR with shfl neighbor carries, unpack 4px/int4, nt stores.
  const int w = lane & 31;
  const int h = lane >> 5;
  const int r = (wv << 1) + h;
  uint64_t v = 0;
#pragma unroll
  for (int i = 0; i <= 2 * RAD; ++i) v |= stage[r + i][w];

  const uint64_t p  = (w == 0)  ? 0ull : __shfl(v, lane - 1);
  const uint64_t nx = (w == 31) ? 0ull : __shfl(v, lane + 1);
  uint64_t res = v;
#pragma unroll
  for (int s = 1; s <= RAD; ++s) {
    res |= (v >> s) | (nx << (64 - s));
    res |= (v << s) | (p >> (64 - s));
  }

  int* optr = out + (long long)(gr0 + (wv << 1)) * WPX;
#pragma unroll
  for (int it = 0; it < 16; ++it) {
    const int f = (it << 6) + lane;             // int4 index in 2-row span
    const int row_l = f >> 9;                   // 512 int4 per row
    const int wi = (f >> 4) & 31;               // 16 int4 per word
    const int sh = (f & 15) << 2;
    const uint64_t bits = __shfl(res, (row_l << 5) + wi) >> sh;
    vint4 o;
    o.x = (int)(bits & 1);
    o.y = (int)((bits >> 1) & 1);
    o.z = (int)((bits >> 2) & 1);
    o.w = (int)((bits >> 3) & 1);
    __builtin_nontemporal_store(o, (vint4*)(optr + (long long)f * 4));
  }
}

extern "C" void kernel_launch(void* const* d_in, const int* in_sizes, int n_in,
                              void* d_out, int out_size, void* d_ws, size_t ws_size,
                              hipStream_t stream) {
  const float* x = (const float*)d_in[0];
  int* out = (int*)d_out;
  uint64_t* packed = (uint64_t*)d_ws;                       // 4 MiB
  unsigned* flags = (unsigned*)((char*)d_ws + (4u << 20));  // 8 KiB, poisoned -> init

  hipLaunchKernelGGL(init_flags, dim3(8), dim3(256), 0, stream, flags);
  // 2048 blocks, 4 waves + 10 KiB LDS each -> 8 blocks/CU co-resident.
  hipLaunchKernelGGL(pc_kernel, dim3(NBLK), dim3(TPB), 0, stream,
                     x, packed, flags, out);
}

// Round 7
// 379.594 us; speedup vs baseline: 1.5306x; 1.5306x over previous
//
#include <hip/hip_runtime.h>
#include <hip/hip_cooperative_groups.h>
#include <stdint.h>

namespace cg = cooperative_groups;

// DilatedMask v6: cooperative single kernel = two proven phases + grid.sync().
// v5's flag-polling failed (424us): agent-scope acquire emits buffer_inv PER
// POLL -> continuous L2 invalidation chip-wide -> 0.5 TB/s. grid.sync() does
// exactly one release(wbl2) + one acquire(inv) per block, and replaces the
// two-kernel launch gap + implicit inter-kernel L2 flush (~10-18us of the
// ~71us kernel region). Phase 1 = v5's proven ballot pack; phase 2 = v4's
// proven 1-barrier dilate (both passed absmax=0.0).

#define HH 2048
#define WPX 2048
#define WW 32            // uint64 words per row (2048 bits)
#define RAD 16
#define ROWS 8           // rows per tile
#define SR (ROWS + 2 * RAD)   // 40 staged rows
#define TPB 256
#define NTILE 2048       // 8 images * 256 tiles

typedef int vint4 __attribute__((ext_vector_type(4)));

__global__ __launch_bounds__(TPB, 8) void coop_kernel(const float* __restrict__ x,
                                                      uint64_t* __restrict__ packed,
                                                      int* __restrict__ out) {
  __shared__ uint64_t stage[SR][WW];            // 10 KiB
  const int t = threadIdx.x;
  const int lane = t & 63;
  const int wv = t >> 6;                        // 0..3
  const int gsz = gridDim.x;

  // ---- phase 1: pack. Tile = 8 rows, 2 rows/wave; lane l's j-th load is px
  // j*64+l so each ballot IS a raster-order packed word. XCD swizzle: image n
  // -> XCD n, so phase-2 halo reads share an XCD L2.
  for (int raw = blockIdx.x; raw < NTILE; raw += gsz) {
    const int b = ((raw & 7) << 8) | (raw >> 3);
    const int gr0 = b * ROWS;
    const float* xr = x + (long long)gr0 * WPX;
    uint64_t* prow = packed + (long long)gr0 * WW;
#pragma unroll
    for (int rr = 0; rr < 2; ++rr) {
      const int row = (wv << 1) + rr;
      const float* rp = xr + (long long)row * WPX + lane;
      uint64_t* pw = prow + row * WW;
#pragma unroll
      for (int bch = 0; bch < 4; ++bch) {
        float v[8];
#pragma unroll
        for (int j = 0; j < 8; ++j)
          v[j] = __builtin_nontemporal_load(rp + (((bch << 3) + j) << 6));
#pragma unroll
        for (int j = 0; j < 8; ++j) {
          const unsigned long long m = __ballot(v[j] == 0.0f);
          if (lane == j) pw[(bch << 3) + j] = m;
        }
      }
    }
  }

  cg::this_grid().sync();   // one release + one acquire per block, grid-wide

  // ---- phase 2: dilate + store (v4 path). Stage 40 packed rows, 1 barrier,
  // per-wave vertical OR from LDS + shfl-carry horizontal OR, nt int4 stores.
  for (int raw = blockIdx.x; raw < NTILE; raw += gsz) {
    const int b = ((raw & 7) << 8) | (raw >> 3);
    const int gr0 = b * ROWS;
    const int n = gr0 >> 11;
    const int h0 = gr0 & (HH - 1);
    const uint64_t* base = packed + (((long long)n) << 11) * WW;
#pragma unroll
    for (int i = 0; i < SR * WW / TPB; ++i) {   // 5 iters, coalesced
      const int idx = i * TPB + t;
      const int rr = idx >> 5;
      const int w_ = idx & 31;
      int hh = h0 + rr - RAD;
      hh = hh < 0 ? 0 : (hh > HH - 1 ? HH - 1 : hh);  // clamp == clipped SAME
      stage[rr][w_] = base[hh * WW + w_];
    }
    __syncthreads();

    const int w = lane & 31;
    const int h = lane >> 5;
    const int r = (wv << 1) + h;                // this lane's output row 0..7
    uint64_t v = 0;
#pragma unroll
    for (int i = 0; i <= 2 * RAD; ++i) v |= stage[r + i][w];

    const uint64_t p  = (w == 0)  ? 0ull : __shfl(v, lane - 1);
    const uint64_t nx = (w == 31) ? 0ull : __shfl(v, lane + 1);
    uint64_t res = v;
#pragma unroll
    for (int s = 1; s <= RAD; ++s) {
      res |= (v >> s) | (nx << (64 - s));
      res |= (v << s) | (p >> (64 - s));
    }

    int* optr = out + (long long)(gr0 + (wv << 1)) * WPX;
#pragma unroll
    for (int it = 0; it < 16; ++it) {
      const int f = (it << 6) + lane;           // int4 index in 2-row span
      const int row_l = f >> 9;
      const int wi = (f >> 4) & 31;
      const int sh = (f & 15) << 2;
      const uint64_t bits = __shfl(res, (row_l << 5) + wi) >> sh;
      vint4 o;
      o.x = (int)(bits & 1);
      o.y = (int)((bits >> 1) & 1);
      o.z = (int)((bits >> 2) & 1);
      o.w = (int)((bits >> 3) & 1);
      __builtin_nontemporal_store(o, (vint4*)(optr + (long long)f * 4));
    }
    __syncthreads();                            // stage reuse guard (multi-tile case)
  }
}

extern "C" void kernel_launch(void* const* d_in, const int* in_sizes, int n_in,
                              void* d_out, int out_size, void* d_ws, size_t ws_size,
                              hipStream_t stream) {
  const float* x = (const float*)d_in[0];
  int* out = (int*)d_out;
  uint64_t* packed = (uint64_t*)d_ws;           // 4 MiB

  // Cooperative grid must be co-resident: size from occupancy query (expect
  // 8 blocks/CU * 256 CU = 2048 = NTILE; grid-stride handles any smaller).
  static int nblk = 0;
  if (nblk == 0) {
    int perCU = 0;
    if (hipOccupancyMaxActiveBlocksPerMultiprocessor(&perCU, coop_kernel, TPB, 0)
            != hipSuccess || perCU < 1)
      perCU = 4;
    int ncu = 0;
    if (hipDeviceGetAttribute(&ncu, hipDeviceAttributeMultiprocessorCount, 0)
            != hipSuccess || ncu < 1)
      ncu = 256;
    long long total = (long long)perCU * ncu;
    nblk = (int)(total < NTILE ? total : NTILE);
  }
  void* args[] = {(void*)&x, (void*)&packed, (void*)&out};
  hipLaunchCooperativeKernel((void*)coop_kernel, dim3(nblk), dim3(TPB),
                             args, 0, stream);
}

// Round 10
// 228.774 us; speedup vs baseline: 2.5397x; 1.6592x over previous
//
#include <hip/hip_runtime.h>
#include <stdint.h>

// DilatedMask v7b: identical to v7 except the memset-units bug fix.
// Harness semantics: out_size is the int32 ELEMENT COUNT (out is read as
// np.int32[(out_size,)]), so the pre-fill must cover out_size words — v7's
// out_size/4 filled only a quarter (absmax=1.0 in the untouched 3/4).
//
// Structure (proven): two-kernel split. Intra-kernel global sync is toxic on
// MI355X (flags=581us, coop grid.sync=379us: acquire-per-poll buffer_inv
// storms). Output is ~all-ones (mask=0 only where a >=17x17 clipped window
// has no zero-pixel), so: pre-fill out with 1 at fill rate (measured 6.7
// TB/s), K1 packs mask bits (raster-order ballot), K2 dilates and stores
// ONLY int4 groups that aren't all-ones (exact for any input: any group with
// a 0 bit is written; all-ones groups rely on the pre-fill).

#define HH_ 2048
#define WW_PX 2048
#define WW 32          // uint64 words per row (2048 bits)
#define RAD 16
#define ROWS 8         // output rows per dilate block
#define SR (ROWS + 2 * RAD)   // 40 staged rows
#define TPB2 256

typedef int vint4 __attribute__((ext_vector_type(4)));

// K1: pack. One block = one row (2048 px), 4 waves x 512 px.
// Lane l's j-th load is px (wv*512) + j*64 + l -> ballot bit l is raster order.
__global__ __launch_bounds__(256) void pack_kernel(const float* __restrict__ x,
                                                   uint64_t* __restrict__ packed) {
  const int t = threadIdx.x;
  const int lane = t & 63;
  const int wv = t >> 6;                       // 0..3
  const float* rp = x + (long long)blockIdx.x * WW_PX + (wv << 9) + lane;
  uint64_t* pr = packed + (long long)blockIdx.x * WW + (wv << 3);

  float v[8];
#pragma unroll
  for (int j = 0; j < 8; ++j)
    v[j] = __builtin_nontemporal_load(rp + (j << 6));
#pragma unroll
  for (int j = 0; j < 8; ++j) {
    const unsigned long long b = __ballot(v[j] == 0.0f);
    if (lane == j) pr[j] = b;
  }
}

// K2: block = 8 output rows. Stage 40 packed rows in LDS (1 barrier), per-wave
// vertical OR from LDS + shfl-carry horizontal OR (v4 proven path), then store
// ONLY the rare not-all-ones int4 groups (out is pre-filled with 1).
__global__ __launch_bounds__(TPB2) void dilate_kernel(const uint64_t* __restrict__ packed,
                                                      int* __restrict__ out) {
  __shared__ uint64_t stage[SR][WW];           // 10 KiB

  const int t = threadIdx.x;
  const int gr0 = blockIdx.x * ROWS;           // 2048 % 8 == 0: never straddles images
  const int n = gr0 >> 11;
  const int h0 = gr0 & 2047;
  const uint64_t* base = packed + (long long)n * (HH_ * WW);

#pragma unroll
  for (int i = 0; i < SR * WW / TPB2; ++i) {   // 5 iters, coalesced
    const int idx = i * TPB2 + t;
    const int rr = idx >> 5;
    const int w_ = idx & 31;
    int hh = h0 + rr - RAD;
    hh = hh < 0 ? 0 : (hh > HH_ - 1 ? HH_ - 1 : hh);  // clamp == clipped SAME
    stage[rr][w_] = base[hh * WW + w_];
  }
  __syncthreads();

  const int lane = t & 63;
  const int wv = t >> 6;                       // 0..3
  const int w = lane & 31;                     // word index
  const int h = lane >> 5;                     // row-within-pair
  const int r = (wv << 1) + h;                 // 0..7: this lane's output row

  uint64_t v = 0;
#pragma unroll
  for (int i = 0; i <= 2 * RAD; ++i) v |= stage[r + i][w];

  const uint64_t p  = (w == 0)  ? 0ull : __shfl(v, lane - 1);
  const uint64_t nx = (w == 31) ? 0ull : __shfl(v, lane + 1);
  uint64_t res = v;
#pragma unroll
  for (int s = 1; s <= RAD; ++s) {
    res |= (v >> s) | (nx << (64 - s));
    res |= (v << s) | (p >> (64 - s));
  }

  // sparse store: out pre-filled with 1; write only int4 groups with a 0 bit.
  int* optr = out + (long long)(gr0 + (wv << 1)) * WW_PX;
#pragma unroll
  for (int it = 0; it < 16; ++it) {
    const int f = (it << 6) + lane;            // int4 index in 2-row span
    const int row_l = f >> 9;                  // 512 int4 per row
    const int wi = (f >> 4) & 31;              // 16 int4 per word
    const int sh = (f & 15) << 2;
    const uint64_t bits = __shfl(res, (row_l << 5) + wi) >> sh;
    if ((bits & 0xFull) != 0xFull) {           // rare: ~never for this input
      vint4 o;
      o.x = (int)(bits & 1);
      o.y = (int)((bits >> 1) & 1);
      o.z = (int)((bits >> 2) & 1);
      o.w = (int)((bits >> 3) & 1);
      __builtin_nontemporal_store(o, (vint4*)(optr + (long long)f * 4));
    }
  }
}

extern "C" void kernel_launch(void* const* d_in, const int* in_sizes, int n_in,
                              void* d_out, int out_size, void* d_ws, size_t ws_size,
                              hipStream_t stream) {
  const float* x = (const float*)d_in[0];
  int* out = (int*)d_out;
  uint64_t* packed = (uint64_t*)d_ws;   // 4 MiB, fully rewritten every call

  // Pre-fill ALL out_size int32 words with 1 at fill rate (~6.7 TB/s).
  // out_size is the element count, NOT bytes (harness reads int32[(out_size,)]).
  hipMemsetD32Async((hipDeviceptr_t)d_out, 1, (size_t)out_size, stream);
  // K1: 16384 rows, one block per row
  hipLaunchKernelGGL(pack_kernel, dim3(16384), dim3(256), 0, stream, x, packed);
  // K2: 16384 global rows / 8 rows per block = 2048 blocks
  hipLaunchKernelGGL(dilate_kernel, dim3(2048), dim3(TPB2), 0, stream, packed, out);
}

// Round 11
// 225.635 us; speedup vs baseline: 2.5750x; 1.0139x over previous
//
#include <hip/hip_runtime.h>
#include <stdint.h>

// DilatedMask FINAL (revert to v4, best measured: 223.6us).
// Two-kernel split — proven the only viable structure on MI355X:
//  * fused single-pass: 249-256us (barrier-coupled phases, 2.6-2.8 TB/s)
//  * flag producer-consumer: 581us (agent-scope acquire-per-poll buffer_inv storm)
//  * cooperative grid.sync: 380us (same coherence-op storm)
//  * memset-prefill + sparse stores: 228.8us (write stream already fill-efficient)
// K1 at read-stream floor (VALU-heavy vs VALU-free A/B tied).
// K2 at write fill efficiency (3-barrier vs 1-barrier tied; memset A/B regressed).
// Total = ~152us harness poison fills (untouchable) + ~72us kernel region,
// vs ~50us idealized serial floor; all overlap levers on this part regress.

#define HH_ 2048
#define WW_PX 2048
#define WW 32          // uint64 words per row (2048 bits)
#define RAD 16
#define ROWS 8         // output rows per dilate block
#define SR (ROWS + 2 * RAD)   // 40 staged rows
#define TPB2 256

typedef int vint4 __attribute__((ext_vector_type(4)));

// K1: pack. One block = one row (2048 px), 4 waves x 512 px.
// Lane l's j-th load is px (wv*512) + j*64 + l -> ballot bit l is raster
// order: each __ballot IS a packed mask word, zero bit-interleave VALU.
__global__ __launch_bounds__(256) void pack_kernel(const float* __restrict__ x,
                                                   uint64_t* __restrict__ packed) {
  const int t = threadIdx.x;
  const int lane = t & 63;
  const int wv = t >> 6;                       // 0..3
  const float* rp = x + (long long)blockIdx.x * WW_PX + (wv << 9) + lane;
  uint64_t* pr = packed + (long long)blockIdx.x * WW + (wv << 3);

  float v[8];
#pragma unroll
  for (int j = 0; j < 8; ++j)
    v[j] = __builtin_nontemporal_load(rp + (j << 6));
#pragma unroll
  for (int j = 0; j < 8; ++j) {
    const unsigned long long b = __ballot(v[j] == 0.0f);
    if (lane == j) pr[j] = b;                  // normal store: stays in cache for K2
  }
}

// K2: block = 8 output rows. Stage 40 packed rows (8 + 2*RAD halo) in LDS,
// ONE barrier, then per-wave independent pipeline: 2 rows/wave, 33-row
// vertical OR from LDS, +-16-bit horizontal OR with shfl neighbor-word
// carries, unpack 4 px per int4, non-temporal coalesced stores.
__global__ __launch_bounds__(TPB2) void dilate_kernel(const uint64_t* __restrict__ packed,
                                                      int* __restrict__ out) {
  __shared__ uint64_t stage[SR][WW];           // 40*32*8 = 10 KiB

  const int t = threadIdx.x;
  const int gr0 = blockIdx.x * ROWS;           // 2048 % 8 == 0: never straddles images
  const int n = gr0 >> 11;
  const int h0 = gr0 & 2047;
  const uint64_t* base = packed + (long long)n * (HH_ * WW);

#pragma unroll
  for (int i = 0; i < SR * WW / TPB2; ++i) {   // 5 iters, coalesced
    const int idx = i * TPB2 + t;
    const int rr = idx >> 5;
    const int w_ = idx & 31;
    int hh = h0 + rr - RAD;
    hh = hh < 0 ? 0 : (hh > HH_ - 1 ? HH_ - 1 : hh);  // clamp == clipped SAME (OR-idempotent)
    stage[rr][w_] = base[hh * WW + w_];
  }
  __syncthreads();                             // the ONLY barrier

  const int lane = t & 63;
  const int wv = t >> 6;                       // 0..3
  const int w = lane & 31;                     // word index
  const int h = lane >> 5;                     // row-within-pair
  const int r = (wv << 1) + h;                 // 0..7: this lane's output row

  uint64_t v = 0;
#pragma unroll
  for (int i = 0; i <= 2 * RAD; ++i) v |= stage[r + i][w];

  const uint64_t p  = (w == 0)  ? 0ull : __shfl(v, lane - 1);
  const uint64_t nx = (w == 31) ? 0ull : __shfl(v, lane + 1);
  uint64_t res = v;
#pragma unroll
  for (int s = 1; s <= RAD; ++s) {
    res |= (v >> s) | (nx << (64 - s));
    res |= (v << s) | (p >> (64 - s));
  }

  // unpack + store: wave owns 2 rows = 1024 int4; 16 iters, coalesced, nt.
  int* optr = out + (long long)(gr0 + (wv << 1)) * WW_PX;
#pragma unroll
  for (int it = 0; it < 16; ++it) {
    const int f = (it << 6) + lane;            // int4 index in 2-row span
    const int row_l = f >> 9;                  // 512 int4 per row
    const int wi = (f >> 4) & 31;              // 16 int4 per word
    const int sh = (f & 15) << 2;
    const uint64_t bits = __shfl(res, (row_l << 5) + wi) >> sh;
    vint4 o;
    o.x = (int)(bits & 1);
    o.y = (int)((bits >> 1) & 1);
    o.z = (int)((bits >> 2) & 1);
    o.w = (int)((bits >> 3) & 1);
    __builtin_nontemporal_store(o, (vint4*)(optr + (long long)f * 4));
  }
}

extern "C" void kernel_launch(void* const* d_in, const int* in_sizes, int n_in,
                              void* d_out, int out_size, void* d_ws, size_t ws_size,
                              hipStream_t stream) {
  const float* x = (const float*)d_in[0];
  int* out = (int*)d_out;
  uint64_t* packed = (uint64_t*)d_ws;   // 8*2048*32*8 B = 4 MiB, fully rewritten every call

  // K1: 16384 rows, one block per row
  hipLaunchKernelGGL(pack_kernel, dim3(16384), dim3(256), 0, stream, x, packed);
  // K2: 16384 global rows / 8 rows per block = 2048 blocks (8/CU)
  hipLaunchKernelGGL(dilate_kernel, dim3(2048), dim3(TPB2), 0, stream, packed, out);
}